// Round 19
// baseline (304.924 us; speedup 1.0000x reference)
//
#include <hip/hip_runtime.h>

typedef __attribute__((ext_vector_type(4))) float f32x4;
typedef __attribute__((ext_vector_type(16))) float f32x16;
typedef __attribute__((ext_vector_type(8))) short bf16x8;
typedef __attribute__((ext_vector_type(4))) unsigned short u16x4;

#define NB 4
#define NT 2048
#define NE 1024
#define NH 16
#define ND 64
#define NM (NB*NT)   // 8192 tokens

__device__ inline unsigned short f2bf(float f){
  unsigned int u = __float_as_uint(f);
  return (unsigned short)((u + 0x7fffu + ((u >> 16) & 1u)) >> 16);
}
__device__ inline float bf2f(unsigned short s){
  return __uint_as_float(((unsigned int)s) << 16);
}
__device__ inline unsigned short f2h(float f){
  union { _Float16 h; unsigned short u; } c;
  c.h = (_Float16)f;
  return c.u;
}
__device__ inline float h2f(unsigned short s){
  union { _Float16 h; unsigned short u; } c;
  c.u = s;
  return (float)c.h;
}
__device__ inline f32x4 mfma16b(bf16x8 a, bf16x8 b, f32x4 c){
  return __builtin_amdgcn_mfma_f32_16x16x32_bf16(a, b, c, 0, 0, 0);
}
__device__ inline f32x4 mfma16h(bf16x8 a, bf16x8 b, f32x4 c){
  return __builtin_amdgcn_mfma_f32_16x16x32_f16(a, b, c, 0, 0, 0);
}
__device__ inline f32x16 mfma32h(bf16x8 a, bf16x8 b, f32x16 c){   // fp16 operands
  return __builtin_amdgcn_mfma_f32_32x32x16_f16(a, b, c, 0, 0, 0);
}
__device__ inline void gload_lds16(const unsigned short* g, unsigned short* l){
  __builtin_amdgcn_global_load_lds(
      (const __attribute__((address_space(1))) void*)g,
      (__attribute__((address_space(3))) void*)l, 16, 0, 0);
}
__device__ inline float max3f(float a, float b, float c){
  float r;
  asm("v_max3_f32 %0, %1, %2, %3" : "=v"(r) : "v"(a), "v"(b), "v"(c));
  return r;
}

// ---------- fp32 x -> single fp16 ----------
__global__ __launch_bounds__(256) void prep_x_k(const float* __restrict__ x,
    unsigned short* __restrict__ xh, int n4){
  int stride = gridDim.x * 256;
  for (int i = blockIdx.x * 256 + threadIdx.x; i < n4; i += stride){
    f32x4 v = ((const f32x4*)x)[i];
    u16x4 o;
    #pragma unroll
    for (int j = 0; j < 4; j++) o[j] = f2h(v[j]);
    ((u16x4*)xh)[i] = o;
  }
}

// ---------- w_qkv [K=1024][3072] -> reordered+transposed single fp16 ----------
// source col = d*48 + kk*16 + h  ->  out row n = kk*1024 + h*64 + d
__global__ __launch_bounds__(256) void prep_wq_k(const float* __restrict__ w,
    unsigned short* __restrict__ wq){
  __shared__ float tile[32][33];
  int tx = threadIdx.x & 31, ty = threadIdx.x >> 5;   // 32 x 8
  int c0 = blockIdx.x * 32, k0 = blockIdx.y * 32;
  #pragma unroll
  for (int i = 0; i < 32; i += 8)
    tile[ty + i][tx] = w[(size_t)(k0 + ty + i) * 3072 + c0 + tx];
  __syncthreads();
  #pragma unroll
  for (int i = 0; i < 32; i += 8){
    int col = c0 + ty + i;
    int d = col / 48, r = col % 48;
    int kk = r >> 4, h = r & 15;
    int n = kk * 1024 + h * 64 + d;
    wq[(size_t)n * NE + k0 + tx] = f2h(tile[tx][ty + i]);
  }
}

// ---------- w_out [1024][1024] -> transposed bf16 [n][k] (coalesced) ----------
__global__ __launch_bounds__(256) void prep_wo_k(const float* __restrict__ w,
    unsigned short* __restrict__ wt){
  __shared__ float tile[32][33];
  int tx = threadIdx.x & 31, ty = threadIdx.x >> 5;
  int n0 = blockIdx.x * 32, k0 = blockIdx.y * 32;
  #pragma unroll
  for (int i = 0; i < 32; i += 8)
    tile[ty + i][tx] = w[(size_t)(k0 + ty + i) * NE + n0 + tx];
  __syncthreads();
  #pragma unroll
  for (int i = 0; i < 32; i += 8)
    wt[(size_t)(n0 + ty + i) * NE + k0 + tx] = f2bf(tile[tx][ty + i]);
}

// ---------- 128x128 GEMM (B^T layout), single-term ----------
// EPI=0: bf16 inputs, Cf[row*N+col] = acc (fp32)
// EPI=1: fp16 inputs, fused QKV scatter: col = kk*1024+h*64+d ->
//        kk=0: Q fp16; kk=1: K fp16 hi/lo; kk=2: V fp16 transposed
template<int EPI>
__global__ __launch_bounds__(256) void gemm_k(
    const unsigned short* __restrict__ A,    // [M][K]
    const unsigned short* __restrict__ Bt,   // [N][K]
    float* __restrict__ Cf,
    unsigned short* __restrict__ Qh,
    unsigned short* __restrict__ Kh, unsigned short* __restrict__ Kl,
    unsigned short* __restrict__ Vt,
    int M, int N, int K){
  __shared__ unsigned short lds[2][128 * 32];
  const int tid = threadIdx.x;
  const int w = tid >> 6, l = tid & 63;
  const int wr = w >> 1, wc = w & 1;
  const int m0 = blockIdx.y * 128, n0 = blockIdx.x * 128;

  f32x4 acc[4][4];
  #pragma unroll
  for (int i = 0; i < 4; i++)
    #pragma unroll
    for (int j = 0; j < 4; j++) acc[i][j] = (f32x4){0.f, 0.f, 0.f, 0.f};

  const int lr = l >> 2;
  const int lkb = (l & 3) * 8;

  for (int k0 = 0; k0 < K; k0 += 32){
    #pragma unroll
    for (int cc = 0; cc < 2; cc++){
      int c = w + cc * 4;
      gload_lds16(A  + (size_t)(m0 + c * 16 + lr) * K + k0 + lkb, &lds[0][c * 512]);
      gload_lds16(Bt + (size_t)(n0 + c * 16 + lr) * K + k0 + lkb, &lds[1][c * 512]);
    }
    __syncthreads();
    bf16x8 af[4], bfr[4];
    #pragma unroll
    for (int mi = 0; mi < 4; mi++)
      af[mi] = *(bf16x8*)&lds[0][(wr * 64 + mi * 16 + (l & 15)) * 32 + (l >> 4) * 8];
    #pragma unroll
    for (int ni = 0; ni < 4; ni++)
      bfr[ni] = *(bf16x8*)&lds[1][(wc * 64 + ni * 16 + (l & 15)) * 32 + (l >> 4) * 8];
    #pragma unroll
    for (int mi = 0; mi < 4; mi++)
      #pragma unroll
      for (int ni = 0; ni < 4; ni++)
        acc[mi][ni] = EPI ? mfma16h(af[mi], bfr[ni], acc[mi][ni])
                          : mfma16b(af[mi], bfr[ni], acc[mi][ni]);
    __syncthreads();
  }

  #pragma unroll
  for (int mi = 0; mi < 4; mi++){
    #pragma unroll
    for (int ni = 0; ni < 4; ni++){
      #pragma unroll
      for (int j = 0; j < 4; j++){
        int row = m0 + wr * 64 + mi * 16 + (l >> 4) * 4 + j;
        int col = n0 + wc * 64 + ni * 16 + (l & 15);
        float v = acc[mi][ni][j];
        if (EPI == 0){
          Cf[(size_t)row * N + col] = v;
        } else {
          int kk = col >> 10, h = (col >> 6) & 15, d = col & 63;
          int bb = row >> 11, t = row & (NT - 1);
          if (kk == 2){
            Vt[((size_t)(bb * NH + h) * ND + d) * NT + t] = f2h(v);
          } else {
            size_t off = ((size_t)(bb * NH + h) * NT + t) * ND + d;
            if (kk == 0){
              Qh[off] = f2h(v);                         // single fp16 Q
            } else {
              unsigned short hi = f2h(v);
              Kh[off] = hi; Kl[off] = f2h(v - h2f(hi)); // fp16 hi/lo K
            }
          }
        }
      }
    }
  }
}

// ---------- flash attention, 32x32 fp16 MFMA, LDS-staged K/V, KVBLK=64 ------
// Round-19: exact revert to round 16 (304us, absmax 0.055, verified).
// Two-chain fp16 QK^T. NOTE: single-chain variants (r17/r18) deterministically
// produced NaN despite clean numerics — codegen hazard, do not retry.
__global__ __launch_bounds__(256, 3) void attn_k(
    const unsigned short* __restrict__ Qh,
    const unsigned short* __restrict__ Kh, const unsigned short* __restrict__ Kl,
    const unsigned short* __restrict__ Vt, unsigned short* __restrict__ O){
  __shared__ unsigned short kh_lds[2][64 * 64];   // 64 kv-rows x 64 d, 8 KB/buf
  __shared__ unsigned short kl_lds[2][64 * 64];
  __shared__ unsigned short vt_lds[2][64 * 64];   // 64 d-rows x 64 t, 8 KB/buf
  const int tid = threadIdx.x;
  const int w = tid >> 6, l = tid & 63;
  const int qi = l & 31, hi = l >> 5;
  const int bid = blockIdx.x;
  const int xcd = bid & 7, slot = bid >> 3;      // slot 0..127
  const int bh_i = xcd + 8 * (slot >> 4);        // 0..63, fixed per XCD group
  const int qt = slot & 15;
  const int b = bh_i >> 4, h = bh_i & 15;
  const int i0 = qt * 128 + w * 32;
  const size_t bh = (size_t)bh_i;

  const unsigned short* KhG = Kh + bh * NT * ND;
  const unsigned short* KlG = Kl + bh * NT * ND;
  const unsigned short* VtG = Vt + bh * ND * NT;

  bf16x8 qh[4];                                   // fp16 payload
  {
    const unsigned short* qb = Qh + (bh * NT + i0 + qi) * ND + hi * 8;
    #pragma unroll
    for (int c = 0; c < 4; c++) qh[c] = *(const bf16x8*)(qb + c * 16);
  }

  f32x16 o0, o1;
  #pragma unroll
  for (int r = 0; r < 16; r++){ o0[r] = 0.f; o1[r] = 0.f; }
  float mrun = -3.0e38f, lrun = 0.f;

  // staging lanes: 8 rows per gload (8 lanes/row); wave w owns rows 16w..16w+15
  const int rk = l >> 3;                       // local row 0..7 within group
  const int ck = (l & 7) ^ rk;                 // swizzled source chunk

  auto STAGE = [&](int buf, int j0){
    gload_lds16(KhG + (size_t)(j0 + 16 * w + rk) * ND + ck * 8,     &kh_lds[buf][(16 * w) * 64]);
    gload_lds16(KhG + (size_t)(j0 + 16 * w + 8 + rk) * ND + ck * 8, &kh_lds[buf][(16 * w + 8) * 64]);
    gload_lds16(KlG + (size_t)(j0 + 16 * w + rk) * ND + ck * 8,     &kl_lds[buf][(16 * w) * 64]);
    gload_lds16(KlG + (size_t)(j0 + 16 * w + 8 + rk) * ND + ck * 8, &kl_lds[buf][(16 * w + 8) * 64]);
    gload_lds16(VtG + (size_t)(16 * w + rk) * NT + j0 + ck * 8,     &vt_lds[buf][(16 * w) * 64]);
    gload_lds16(VtG + (size_t)(16 * w + 8 + rk) * NT + j0 + ck * 8, &vt_lds[buf][(16 * w + 8) * 64]);
  };

  auto STEP = [&](int buf, int half){
    const char* KH = (const char*)&kh_lds[buf][0];
    const char* KL = (const char*)&kl_lds[buf][0];
    const char* VT = (const char*)&vt_lds[buf][0];
    // K fragments: row half*32+qi, chunk 2c+hi, swizzled slot (row&7 = qi&7)
    bf16x8 kh[4], kl[4];
    #pragma unroll
    for (int c = 0; c < 4; c++){
      int off = (half * 32 + qi) * 128 + (((2 * c + hi) ^ (qi & 7)) * 16);
      kh[c] = *(const bf16x8*)(KH + off);
      kl[c] = *(const bf16x8*)(KL + off);
    }

    // 2-chain fp16 QK^T: S = qh*kh + qh*kl  (K = kh+kl near-exact)
    f32x16 t1, t2;
    #pragma unroll
    for (int r = 0; r < 16; r++){ t1[r] = 0.f; t2[r] = 0.f; }
    __builtin_amdgcn_s_setprio(1);
    #pragma unroll
    for (int c = 0; c < 4; c++){
      t1 = mfma32h(kh[c], qh[c], t1);
      t2 = mfma32h(kl[c], qh[c], t2);
    }
    __builtin_amdgcn_s_setprio(0);
    f32x16 s = t1 + t2;

    // V fragments (issue early): d-row dt*32+qi, t-slot half*4+2k0+hi
    bf16x8 vb[2][2];
    #pragma unroll
    for (int dt = 0; dt < 2; dt++)
      #pragma unroll
      for (int k0 = 0; k0 < 2; k0++){
        int off = (dt * 32 + qi) * 128 + (((half * 4 + 2 * k0 + hi) ^ (qi & 7)) * 16);
        vb[dt][k0] = *(const bf16x8*)(VT + off);
      }

    // online softmax; stats indexed by q = lane&31; max3 tree
    float m1 = max3f(s[0], s[1], s[2]);
    float m2 = max3f(s[3], s[4], s[5]);
    float m3 = max3f(s[6], s[7], s[8]);
    float m4 = max3f(s[9], s[10], s[11]);
    float m5 = max3f(s[12], s[13], s[14]);
    float pm = fmaxf(max3f(m1, m2, m3), max3f(m4, m5, s[15]));
    pm = fmaxf(pm, __shfl_xor(pm, 32));
    float Lm = pm * 8.0f;
    if (!__all(Lm <= mrun + 8.0f)){      // defer-max (T13), THR=8
      float nm = fmaxf(mrun, Lm);
      float sc = __expf(mrun - nm);
      mrun = nm;
      lrun *= sc;
      #pragma unroll
      for (int r = 0; r < 16; r++){      // O row = crow(r,hi): gather row's sc
        int mrow = (r & 3) + 8 * (r >> 2) + 4 * hi;
        float scr = __shfl(sc, mrow);
        o0[r] *= scr;
        o1[r] *= scr;
      }
    }
    float p[16];
    #pragma unroll
    for (int r = 0; r < 16; r++) p[r] = __expf(fmaf(s[r], 8.0f, -mrun));
    float u8[8], u4[4];
    #pragma unroll
    for (int i = 0; i < 8; i++) u8[i] = p[2 * i] + p[2 * i + 1];
    #pragma unroll
    for (int i = 0; i < 4; i++) u4[i] = u8[2 * i] + u8[2 * i + 1];
    float rs = (u4[0] + u4[1]) + (u4[2] + u4[3]);
    rs += __shfl_xor(rs, 32);
    lrun += rs;

    // P -> fp16 via packed cvt, then lane<->lane+32 exchange (no LDS)
    unsigned int pk[8];
    #pragma unroll
    for (int i = 0; i < 8; i++)
      asm("v_cvt_pkrtz_f16_f32 %0, %1, %2" : "=v"(pk[i]) : "v"(p[2 * i]), "v"(p[2 * i + 1]));
    unsigned int sw[8];
    #pragma unroll
    for (int i = 0; i < 8; i++) sw[i] = __shfl_xor(pk[i], 32);

    union { unsigned int u[4]; bf16x8 v; } pa0, pa1;
    pa0.u[0] = hi ? sw[2] : pk[0];
    pa0.u[1] = hi ? sw[3] : pk[1];
    pa0.u[2] = hi ? pk[2] : sw[0];
    pa0.u[3] = hi ? pk[3] : sw[1];
    pa1.u[0] = hi ? sw[6] : pk[4];
    pa1.u[1] = hi ? sw[7] : pk[5];
    pa1.u[2] = hi ? pk[6] : sw[4];
    pa1.u[3] = hi ? pk[7] : sw[5];

    __builtin_amdgcn_s_setprio(1);
    o0 = mfma32h(pa0.v, vb[0][0], o0);
    o0 = mfma32h(pa1.v, vb[0][1], o0);
    o1 = mfma32h(pa0.v, vb[1][0], o1);
    o1 = mfma32h(pa1.v, vb[1][1], o1);
    __builtin_amdgcn_s_setprio(0);
  };

  STAGE(0, 0);
  asm volatile("s_waitcnt vmcnt(0)" ::: "memory");
  __syncthreads();
  int buf = 0;
  for (int j0 = 0; j0 < NT; j0 += 64){
    if (j0 + 64 < NT) STAGE(buf ^ 1, j0 + 64);   // prefetch next 64-kv tile
    STEP(buf, 0);
    STEP(buf, 1);
    __syncthreads();                              // drains vmcnt+lgkm, then barrier
    buf ^= 1;
  }

  // normalize (lrun for row mrow lives in lane mrow) and store (bf16 Obuf)
  float rl = 1.0f / lrun;
  #pragma unroll
  for (int r = 0; r < 16; r++){
    int mrow = (r & 3) + 8 * (r >> 2) + 4 * hi;
    float f = __shfl(rl, mrow);
    size_t base = ((size_t)b * NT + i0 + mrow) * NE + h * ND + qi;
    O[base]      = f2bf(o0[r] * f);
    O[base + 32] = f2bf(o1[r] * f);
  }
}

extern "C" void kernel_launch(void* const* d_in, const int* in_sizes, int n_in,
                              void* d_out, int out_size, void* d_ws, size_t ws_size,
                              hipStream_t stream){
  const float* x     = (const float*)d_in[0];
  const float* w_qkv = (const float*)d_in[1];
  const float* w_out = (const float*)d_in[2];
  float* out = (float*)d_out;

  char* ws = (char*)d_ws;
  const size_t SZ_X  = (size_t)NM * NE * 2;          // 16.78 MB
  const size_t SZ_WQ = (size_t)3072 * NE * 2;        // 6.29 MB
  const size_t SZ_WO = (size_t)NE * NE * 2;          // 2.10 MB
  const size_t SZ_T  = (size_t)NB * NH * NT * ND * 2;// 16.78 MB

  unsigned short* xh  = (unsigned short*)(ws);
  unsigned short* wq  = (unsigned short*)(ws + SZ_X);
  unsigned short* wto = (unsigned short*)(ws + SZ_X + SZ_WQ);
  unsigned short* Qh  = (unsigned short*)(ws + SZ_X + SZ_WQ + SZ_WO);
  unsigned short* Kh  = Qh + (SZ_T / 2);
  unsigned short* Kl  = Qh + 2 * (SZ_T / 2);
  unsigned short* Vt  = Qh + 3 * (SZ_T / 2);   // own slot (x live during fused GEMM)
  unsigned short* Obuf = xh;                   // x dead after fused GEMM

  const size_t NEED = SZ_X + SZ_WQ + SZ_WO + 4 * SZ_T;  // ~92 MB
  if (ws_size < NEED) return;

  prep_x_k<<<2048, 256, 0, stream>>>(x, xh, NM * NE / 4);
  prep_wq_k<<<dim3(3072 / 32, 1024 / 32), 256, 0, stream>>>(w_qkv, wq);
  prep_wo_k<<<dim3(1024 / 32, 1024 / 32), 256, 0, stream>>>(w_out, wto);
  // fused QKV projection: single-term fp16, N=3072
  gemm_k<1><<<dim3(3072 / 128, NM / 128), 256, 0, stream>>>(
      xh, wq, nullptr, Qh, Kh, Kl, Vt, NM, 3072, NE);
  attn_k<<<dim3(1024), 256, 0, stream>>>(Qh, Kh, Kl, Vt, Obuf);
  gemm_k<0><<<dim3(NE / 128, NM / 128), 256, 0, stream>>>(
      Obuf, wto, out, nullptr, nullptr, nullptr, nullptr, NM, NE, NE);
}

// Round 20
// 295.608 us; speedup vs baseline: 1.0315x; 1.0315x over previous
//
#include <hip/hip_runtime.h>

typedef __attribute__((ext_vector_type(4))) float f32x4;
typedef __attribute__((ext_vector_type(16))) float f32x16;
typedef __attribute__((ext_vector_type(8))) short bf16x8;
typedef __attribute__((ext_vector_type(4))) unsigned short u16x4;

#define NB 4
#define NT 2048
#define NE 1024
#define NH 16
#define ND 64
#define NM (NB*NT)   // 8192 tokens

__device__ inline unsigned short f2bf(float f){
  unsigned int u = __float_as_uint(f);
  return (unsigned short)((u + 0x7fffu + ((u >> 16) & 1u)) >> 16);
}
__device__ inline float bf2f(unsigned short s){
  return __uint_as_float(((unsigned int)s) << 16);
}
__device__ inline unsigned short f2h(float f){
  union { _Float16 h; unsigned short u; } c;
  c.h = (_Float16)f;
  return c.u;
}
__device__ inline float h2f(unsigned short s){
  union { _Float16 h; unsigned short u; } c;
  c.u = s;
  return (float)c.h;
}
__device__ inline f32x4 mfma16b(bf16x8 a, bf16x8 b, f32x4 c){
  return __builtin_amdgcn_mfma_f32_16x16x32_bf16(a, b, c, 0, 0, 0);
}
__device__ inline f32x4 mfma16h(bf16x8 a, bf16x8 b, f32x4 c){
  return __builtin_amdgcn_mfma_f32_16x16x32_f16(a, b, c, 0, 0, 0);
}
__device__ inline f32x16 mfma32h(bf16x8 a, bf16x8 b, f32x16 c){   // fp16 operands
  return __builtin_amdgcn_mfma_f32_32x32x16_f16(a, b, c, 0, 0, 0);
}
__device__ inline void gload_lds16(const unsigned short* g, unsigned short* l){
  __builtin_amdgcn_global_load_lds(
      (const __attribute__((address_space(1))) void*)g,
      (__attribute__((address_space(3))) void*)l, 16, 0, 0);
}
__device__ inline float max3f(float a, float b, float c){
  float r;
  asm("v_max3_f32 %0, %1, %2, %3" : "=v"(r) : "v"(a), "v"(b), "v"(c));
  return r;
}

// ---------- fp32 x -> single fp16 ----------
__global__ __launch_bounds__(256) void prep_x_k(const float* __restrict__ x,
    unsigned short* __restrict__ xh, int n4){
  int stride = gridDim.x * 256;
  for (int i = blockIdx.x * 256 + threadIdx.x; i < n4; i += stride){
    f32x4 v = ((const f32x4*)x)[i];
    u16x4 o;
    #pragma unroll
    for (int j = 0; j < 4; j++) o[j] = f2h(v[j]);
    ((u16x4*)xh)[i] = o;
  }
}

// ---------- w_qkv [K=1024][3072] -> reordered+transposed single fp16 ----------
// source col = d*48 + kk*16 + h  ->  out row n = kk*1024 + h*64 + d
__global__ __launch_bounds__(256) void prep_wq_k(const float* __restrict__ w,
    unsigned short* __restrict__ wq){
  __shared__ float tile[32][33];
  int tx = threadIdx.x & 31, ty = threadIdx.x >> 5;   // 32 x 8
  int c0 = blockIdx.x * 32, k0 = blockIdx.y * 32;
  #pragma unroll
  for (int i = 0; i < 32; i += 8)
    tile[ty + i][tx] = w[(size_t)(k0 + ty + i) * 3072 + c0 + tx];
  __syncthreads();
  #pragma unroll
  for (int i = 0; i < 32; i += 8){
    int col = c0 + ty + i;
    int d = col / 48, r = col % 48;
    int kk = r >> 4, h = r & 15;
    int n = kk * 1024 + h * 64 + d;
    wq[(size_t)n * NE + k0 + tx] = f2h(tile[tx][ty + i]);
  }
}

// ---------- w_out [1024][1024] -> transposed bf16 [n][k] (coalesced) ----------
__global__ __launch_bounds__(256) void prep_wo_k(const float* __restrict__ w,
    unsigned short* __restrict__ wt){
  __shared__ float tile[32][33];
  int tx = threadIdx.x & 31, ty = threadIdx.x >> 5;
  int n0 = blockIdx.x * 32, k0 = blockIdx.y * 32;
  #pragma unroll
  for (int i = 0; i < 32; i += 8)
    tile[ty + i][tx] = w[(size_t)(k0 + ty + i) * NE + n0 + tx];
  __syncthreads();
  #pragma unroll
  for (int i = 0; i < 32; i += 8)
    wt[(size_t)(n0 + ty + i) * NE + k0 + tx] = f2bf(tile[tx][ty + i]);
}

// ---------- 128x128 GEMM (B^T layout), single-term ----------
// EPI=0: bf16 inputs, Cf[row*N+col] = acc (fp32)
// EPI=1: fp16 inputs, fused QKV scatter: col = kk*1024+h*64+d ->
//        kk=0: Q fp16; kk=1: K fp16 hi/lo; kk=2: V fp16 transposed
template<int EPI>
__global__ __launch_bounds__(256) void gemm_k(
    const unsigned short* __restrict__ A,    // [M][K]
    const unsigned short* __restrict__ Bt,   // [N][K]
    float* __restrict__ Cf,
    unsigned short* __restrict__ Qh,
    unsigned short* __restrict__ Kh, unsigned short* __restrict__ Kl,
    unsigned short* __restrict__ Vt,
    int M, int N, int K){
  __shared__ unsigned short lds[2][128 * 32];
  const int tid = threadIdx.x;
  const int w = tid >> 6, l = tid & 63;
  const int wr = w >> 1, wc = w & 1;
  const int m0 = blockIdx.y * 128, n0 = blockIdx.x * 128;

  f32x4 acc[4][4];
  #pragma unroll
  for (int i = 0; i < 4; i++)
    #pragma unroll
    for (int j = 0; j < 4; j++) acc[i][j] = (f32x4){0.f, 0.f, 0.f, 0.f};

  const int lr = l >> 2;
  const int lkb = (l & 3) * 8;

  for (int k0 = 0; k0 < K; k0 += 32){
    #pragma unroll
    for (int cc = 0; cc < 2; cc++){
      int c = w + cc * 4;
      gload_lds16(A  + (size_t)(m0 + c * 16 + lr) * K + k0 + lkb, &lds[0][c * 512]);
      gload_lds16(Bt + (size_t)(n0 + c * 16 + lr) * K + k0 + lkb, &lds[1][c * 512]);
    }
    __syncthreads();
    bf16x8 af[4], bfr[4];
    #pragma unroll
    for (int mi = 0; mi < 4; mi++)
      af[mi] = *(bf16x8*)&lds[0][(wr * 64 + mi * 16 + (l & 15)) * 32 + (l >> 4) * 8];
    #pragma unroll
    for (int ni = 0; ni < 4; ni++)
      bfr[ni] = *(bf16x8*)&lds[1][(wc * 64 + ni * 16 + (l & 15)) * 32 + (l >> 4) * 8];
    #pragma unroll
    for (int mi = 0; mi < 4; mi++)
      #pragma unroll
      for (int ni = 0; ni < 4; ni++)
        acc[mi][ni] = EPI ? mfma16h(af[mi], bfr[ni], acc[mi][ni])
                          : mfma16b(af[mi], bfr[ni], acc[mi][ni]);
    __syncthreads();
  }

  #pragma unroll
  for (int mi = 0; mi < 4; mi++){
    #pragma unroll
    for (int ni = 0; ni < 4; ni++){
      #pragma unroll
      for (int j = 0; j < 4; j++){
        int row = m0 + wr * 64 + mi * 16 + (l >> 4) * 4 + j;
        int col = n0 + wc * 64 + ni * 16 + (l & 15);
        float v = acc[mi][ni][j];
        if (EPI == 0){
          Cf[(size_t)row * N + col] = v;
        } else {
          int kk = col >> 10, h = (col >> 6) & 15, d = col & 63;
          int bb = row >> 11, t = row & (NT - 1);
          if (kk == 2){
            Vt[((size_t)(bb * NH + h) * ND + d) * NT + t] = f2h(v);
          } else {
            size_t off = ((size_t)(bb * NH + h) * NT + t) * ND + d;
            if (kk == 0){
              Qh[off] = f2h(v);                         // single fp16 Q
            } else {
              unsigned short hi = f2h(v);
              Kh[off] = hi; Kl[off] = f2h(v - h2f(hi)); // fp16 hi/lo K
            }
          }
        }
      }
    }
  }
}

// ---------- flash attention, 32x32 fp16 MFMA, LDS-staged K/V, KVBLK=64 ------
// Round-20: each wave owns TWO 32-row q-tiles (A at i0A, B at i0A+128); block
// covers 256 q-rows; grid 512 = exactly 2 blocks/CU (balanced). Per staged
// K/V buffer: 4 STEPs instead of 2 -> barrier+vmcnt-drain cost per unit work
// halved, per-CU K/V fetch halved. STEP body verbatim from proven r16/r19,
// parameterized by per-tile state (named A/B objects, static indexing).
// Two-chain QK^T kept (single-chain = NaN codegen trap, r17/r18 — do not retry).
__global__ __launch_bounds__(256, 2) void attn_k(
    const unsigned short* __restrict__ Qh,
    const unsigned short* __restrict__ Kh, const unsigned short* __restrict__ Kl,
    const unsigned short* __restrict__ Vt, unsigned short* __restrict__ O){
  __shared__ unsigned short kh_lds[2][64 * 64];   // 64 kv-rows x 64 d, 8 KB/buf
  __shared__ unsigned short kl_lds[2][64 * 64];
  __shared__ unsigned short vt_lds[2][64 * 64];   // 64 d-rows x 64 t, 8 KB/buf
  const int tid = threadIdx.x;
  const int w = tid >> 6, l = tid & 63;
  const int qi = l & 31, hi = l >> 5;
  const int bid = blockIdx.x;
  const int xcd = bid & 7, slot = bid >> 3;      // slot 0..63
  const int bh_i = xcd + 8 * (slot >> 3);        // 0..63, fixed per XCD group
  const int qt = slot & 7;
  const int b = bh_i >> 4, h = bh_i & 15;
  const int i0A = qt * 256 + w * 32;
  const int i0B = i0A + 128;
  const size_t bh = (size_t)bh_i;

  const unsigned short* KhG = Kh + bh * NT * ND;
  const unsigned short* KlG = Kl + bh * NT * ND;
  const unsigned short* VtG = Vt + bh * ND * NT;

  bf16x8 qhA[4], qhB[4];                          // fp16 payload
  {
    const unsigned short* qa = Qh + (bh * NT + i0A + qi) * ND + hi * 8;
    const unsigned short* qb = Qh + (bh * NT + i0B + qi) * ND + hi * 8;
    #pragma unroll
    for (int c = 0; c < 4; c++){
      qhA[c] = *(const bf16x8*)(qa + c * 16);
      qhB[c] = *(const bf16x8*)(qb + c * 16);
    }
  }

  f32x16 oA0, oA1, oB0, oB1;
  #pragma unroll
  for (int r = 0; r < 16; r++){ oA0[r] = 0.f; oA1[r] = 0.f; oB0[r] = 0.f; oB1[r] = 0.f; }
  float mrunA = -3.0e38f, lrunA = 0.f;
  float mrunB = -3.0e38f, lrunB = 0.f;

  // staging lanes: 8 rows per gload (8 lanes/row); wave w owns rows 16w..16w+15
  const int rk = l >> 3;                       // local row 0..7 within group
  const int ck = (l & 7) ^ rk;                 // swizzled source chunk

  auto STAGE = [&](int buf, int j0){
    gload_lds16(KhG + (size_t)(j0 + 16 * w + rk) * ND + ck * 8,     &kh_lds[buf][(16 * w) * 64]);
    gload_lds16(KhG + (size_t)(j0 + 16 * w + 8 + rk) * ND + ck * 8, &kh_lds[buf][(16 * w + 8) * 64]);
    gload_lds16(KlG + (size_t)(j0 + 16 * w + rk) * ND + ck * 8,     &kl_lds[buf][(16 * w) * 64]);
    gload_lds16(KlG + (size_t)(j0 + 16 * w + 8 + rk) * ND + ck * 8, &kl_lds[buf][(16 * w + 8) * 64]);
    gload_lds16(VtG + (size_t)(16 * w + rk) * NT + j0 + ck * 8,     &vt_lds[buf][(16 * w) * 64]);
    gload_lds16(VtG + (size_t)(16 * w + 8 + rk) * NT + j0 + ck * 8, &vt_lds[buf][(16 * w + 8) * 64]);
  };

  auto STEP = [&](int buf, int half, const bf16x8 (&qh)[4],
                  f32x16& o0, f32x16& o1, float& mrun, float& lrun){
    const char* KH = (const char*)&kh_lds[buf][0];
    const char* KL = (const char*)&kl_lds[buf][0];
    const char* VT = (const char*)&vt_lds[buf][0];
    // K fragments: row half*32+qi, chunk 2c+hi, swizzled slot (row&7 = qi&7)
    bf16x8 kh[4], kl[4];
    #pragma unroll
    for (int c = 0; c < 4; c++){
      int off = (half * 32 + qi) * 128 + (((2 * c + hi) ^ (qi & 7)) * 16);
      kh[c] = *(const bf16x8*)(KH + off);
      kl[c] = *(const bf16x8*)(KL + off);
    }

    // 2-chain fp16 QK^T: S = qh*kh + qh*kl  (K = kh+kl near-exact)
    f32x16 t1, t2;
    #pragma unroll
    for (int r = 0; r < 16; r++){ t1[r] = 0.f; t2[r] = 0.f; }
    __builtin_amdgcn_s_setprio(1);
    #pragma unroll
    for (int c = 0; c < 4; c++){
      t1 = mfma32h(kh[c], qh[c], t1);
      t2 = mfma32h(kl[c], qh[c], t2);
    }
    __builtin_amdgcn_s_setprio(0);
    f32x16 s = t1 + t2;

    // V fragments (issue early): d-row dt*32+qi, t-slot half*4+2k0+hi
    bf16x8 vb[2][2];
    #pragma unroll
    for (int dt = 0; dt < 2; dt++)
      #pragma unroll
      for (int k0 = 0; k0 < 2; k0++){
        int off = (dt * 32 + qi) * 128 + (((half * 4 + 2 * k0 + hi) ^ (qi & 7)) * 16);
        vb[dt][k0] = *(const bf16x8*)(VT + off);
      }

    // online softmax; stats indexed by q = lane&31; max3 tree
    float m1 = max3f(s[0], s[1], s[2]);
    float m2 = max3f(s[3], s[4], s[5]);
    float m3 = max3f(s[6], s[7], s[8]);
    float m4 = max3f(s[9], s[10], s[11]);
    float m5 = max3f(s[12], s[13], s[14]);
    float pm = fmaxf(max3f(m1, m2, m3), max3f(m4, m5, s[15]));
    pm = fmaxf(pm, __shfl_xor(pm, 32));
    float Lm = pm * 8.0f;
    if (!__all(Lm <= mrun + 8.0f)){      // defer-max (T13), THR=8
      float nm = fmaxf(mrun, Lm);
      float sc = __expf(mrun - nm);
      mrun = nm;
      lrun *= sc;
      #pragma unroll
      for (int r = 0; r < 16; r++){      // O row = crow(r,hi): gather row's sc
        int mrow = (r & 3) + 8 * (r >> 2) + 4 * hi;
        float scr = __shfl(sc, mrow);
        o0[r] *= scr;
        o1[r] *= scr;
      }
    }
    float p[16];
    #pragma unroll
    for (int r = 0; r < 16; r++) p[r] = __expf(fmaf(s[r], 8.0f, -mrun));
    float u8[8], u4[4];
    #pragma unroll
    for (int i = 0; i < 8; i++) u8[i] = p[2 * i] + p[2 * i + 1];
    #pragma unroll
    for (int i = 0; i < 4; i++) u4[i] = u8[2 * i] + u8[2 * i + 1];
    float rs = (u4[0] + u4[1]) + (u4[2] + u4[3]);
    rs += __shfl_xor(rs, 32);
    lrun += rs;

    // P -> fp16 via packed cvt, then lane<->lane+32 exchange (no LDS)
    unsigned int pk[8];
    #pragma unroll
    for (int i = 0; i < 8; i++)
      asm("v_cvt_pkrtz_f16_f32 %0, %1, %2" : "=v"(pk[i]) : "v"(p[2 * i]), "v"(p[2 * i + 1]));
    unsigned int sw[8];
    #pragma unroll
    for (int i = 0; i < 8; i++) sw[i] = __shfl_xor(pk[i], 32);

    union { unsigned int u[4]; bf16x8 v; } pa0, pa1;
    pa0.u[0] = hi ? sw[2] : pk[0];
    pa0.u[1] = hi ? sw[3] : pk[1];
    pa0.u[2] = hi ? pk[2] : sw[0];
    pa0.u[3] = hi ? pk[3] : sw[1];
    pa1.u[0] = hi ? sw[6] : pk[4];
    pa1.u[1] = hi ? sw[7] : pk[5];
    pa1.u[2] = hi ? pk[6] : sw[4];
    pa1.u[3] = hi ? pk[7] : sw[5];

    __builtin_amdgcn_s_setprio(1);
    o0 = mfma32h(pa0.v, vb[0][0], o0);
    o0 = mfma32h(pa1.v, vb[0][1], o0);
    o1 = mfma32h(pa0.v, vb[1][0], o1);
    o1 = mfma32h(pa1.v, vb[1][1], o1);
    __builtin_amdgcn_s_setprio(0);
  };

  STAGE(0, 0);
  asm volatile("s_waitcnt vmcnt(0)" ::: "memory");
  __syncthreads();
  int buf = 0;
  for (int j0 = 0; j0 < NT; j0 += 64){
    if (j0 + 64 < NT) STAGE(buf ^ 1, j0 + 64);   // prefetch next 64-kv tile
    STEP(buf, 0, qhA, oA0, oA1, mrunA, lrunA);
    STEP(buf, 1, qhA, oA0, oA1, mrunA, lrunA);
    STEP(buf, 0, qhB, oB0, oB1, mrunB, lrunB);
    STEP(buf, 1, qhB, oB0, oB1, mrunB, lrunB);
    __syncthreads();                              // drains vmcnt+lgkm, then barrier
    buf ^= 1;
  }

  // normalize (lrun for row mrow lives in lane mrow) and store (bf16 Obuf)
  float rlA = 1.0f / lrunA;
  float rlB = 1.0f / lrunB;
  #pragma unroll
  for (int r = 0; r < 16; r++){
    int mrow = (r & 3) + 8 * (r >> 2) + 4 * hi;
    float fA = __shfl(rlA, mrow);
    float fB = __shfl(rlB, mrow);
    size_t baseA = ((size_t)b * NT + i0A + mrow) * NE + h * ND + qi;
    size_t baseB = ((size_t)b * NT + i0B + mrow) * NE + h * ND + qi;
    O[baseA]      = f2bf(oA0[r] * fA);
    O[baseA + 32] = f2bf(oA1[r] * fA);
    O[baseB]      = f2bf(oB0[r] * fB);
    O[baseB + 32] = f2bf(oB1[r] * fB);
  }
}

extern "C" void kernel_launch(void* const* d_in, const int* in_sizes, int n_in,
                              void* d_out, int out_size, void* d_ws, size_t ws_size,
                              hipStream_t stream){
  const float* x     = (const float*)d_in[0];
  const float* w_qkv = (const float*)d_in[1];
  const float* w_out = (const float*)d_in[2];
  float* out = (float*)d_out;

  char* ws = (char*)d_ws;
  const size_t SZ_X  = (size_t)NM * NE * 2;          // 16.78 MB
  const size_t SZ_WQ = (size_t)3072 * NE * 2;        // 6.29 MB
  const size_t SZ_WO = (size_t)NE * NE * 2;          // 2.10 MB
  const size_t SZ_T  = (size_t)NB * NH * NT * ND * 2;// 16.78 MB

  unsigned short* xh  = (unsigned short*)(ws);
  unsigned short* wq  = (unsigned short*)(ws + SZ_X);
  unsigned short* wto = (unsigned short*)(ws + SZ_X + SZ_WQ);
  unsigned short* Qh  = (unsigned short*)(ws + SZ_X + SZ_WQ + SZ_WO);
  unsigned short* Kh  = Qh + (SZ_T / 2);
  unsigned short* Kl  = Qh + 2 * (SZ_T / 2);
  unsigned short* Vt  = Qh + 3 * (SZ_T / 2);   // own slot (x live during fused GEMM)
  unsigned short* Obuf = xh;                   // x dead after fused GEMM

  const size_t NEED = SZ_X + SZ_WQ + SZ_WO + 4 * SZ_T;  // ~92 MB
  if (ws_size < NEED) return;

  prep_x_k<<<2048, 256, 0, stream>>>(x, xh, NM * NE / 4);
  prep_wq_k<<<dim3(3072 / 32, 1024 / 32), 256, 0, stream>>>(w_qkv, wq);
  prep_wo_k<<<dim3(1024 / 32, 1024 / 32), 256, 0, stream>>>(w_out, wto);
  // fused QKV projection: single-term fp16, N=3072
  gemm_k<1><<<dim3(3072 / 128, NM / 128), 256, 0, stream>>>(
      xh, wq, nullptr, Qh, Kh, Kl, Vt, NM, 3072, NE);
  attn_k<<<dim3(512), 256, 0, stream>>>(Qh, Kh, Kl, Vt, Obuf);
  gemm_k<0><<<dim3(NE / 128, NM / 128), 256, 0, stream>>>(
      Obuf, wto, out, nullptr, nullptr, nullptr, nullptr, NM, NE, NE);
}

// Round 22
// 295.515 us; speedup vs baseline: 1.0318x; 1.0003x over previous
//
#include <hip/hip_runtime.h>

typedef __attribute__((ext_vector_type(4))) float f32x4;
typedef __attribute__((ext_vector_type(16))) float f32x16;
typedef __attribute__((ext_vector_type(8))) short bf16x8;
typedef __attribute__((ext_vector_type(4))) unsigned short u16x4;

#define NB 4
#define NT 2048
#define NE 1024
#define NH 16
#define ND 64
#define NM (NB*NT)   // 8192 tokens

__device__ inline unsigned short f2bf(float f){
  unsigned int u = __float_as_uint(f);
  return (unsigned short)((u + 0x7fffu + ((u >> 16) & 1u)) >> 16);
}
__device__ inline float bf2f(unsigned short s){
  return __uint_as_float(((unsigned int)s) << 16);
}
__device__ inline unsigned short f2h(float f){
  union { _Float16 h; unsigned short u; } c;
  c.h = (_Float16)f;
  return c.u;
}
__device__ inline float h2f(unsigned short s){
  union { _Float16 h; unsigned short u; } c;
  c.u = s;
  return (float)c.h;
}
__device__ inline f32x4 mfma16b(bf16x8 a, bf16x8 b, f32x4 c){
  return __builtin_amdgcn_mfma_f32_16x16x32_bf16(a, b, c, 0, 0, 0);
}
__device__ inline f32x4 mfma16h(bf16x8 a, bf16x8 b, f32x4 c){
  return __builtin_amdgcn_mfma_f32_16x16x32_f16(a, b, c, 0, 0, 0);
}
__device__ inline f32x16 mfma32h(bf16x8 a, bf16x8 b, f32x16 c){   // fp16 operands
  return __builtin_amdgcn_mfma_f32_32x32x16_f16(a, b, c, 0, 0, 0);
}
__device__ inline void gload_lds16(const unsigned short* g, unsigned short* l){
  __builtin_amdgcn_global_load_lds(
      (const __attribute__((address_space(1))) void*)g,
      (__attribute__((address_space(3))) void*)l, 16, 0, 0);
}
__device__ inline float max3f(float a, float b, float c){
  float r;
  asm("v_max3_f32 %0, %1, %2, %3" : "=v"(r) : "v"(a), "v"(b), "v"(c));
  return r;
}

// ---------- fp32 x -> single fp16 ----------
__global__ __launch_bounds__(256) void prep_x_k(const float* __restrict__ x,
    unsigned short* __restrict__ xh, int n4){
  int stride = gridDim.x * 256;
  for (int i = blockIdx.x * 256 + threadIdx.x; i < n4; i += stride){
    f32x4 v = ((const f32x4*)x)[i];
    u16x4 o;
    #pragma unroll
    for (int j = 0; j < 4; j++) o[j] = f2h(v[j]);
    ((u16x4*)xh)[i] = o;
  }
}

// ---------- w_qkv [K=1024][3072] -> reordered+transposed single fp16 ----------
// source col = d*48 + kk*16 + h  ->  out row n = kk*1024 + h*64 + d
__global__ __launch_bounds__(256) void prep_wq_k(const float* __restrict__ w,
    unsigned short* __restrict__ wq){
  __shared__ float tile[32][33];
  int tx = threadIdx.x & 31, ty = threadIdx.x >> 5;   // 32 x 8
  int c0 = blockIdx.x * 32, k0 = blockIdx.y * 32;
  #pragma unroll
  for (int i = 0; i < 32; i += 8)
    tile[ty + i][tx] = w[(size_t)(k0 + ty + i) * 3072 + c0 + tx];
  __syncthreads();
  #pragma unroll
  for (int i = 0; i < 32; i += 8){
    int col = c0 + ty + i;
    int d = col / 48, r = col % 48;
    int kk = r >> 4, h = r & 15;
    int n = kk * 1024 + h * 64 + d;
    wq[(size_t)n * NE + k0 + tx] = f2h(tile[tx][ty + i]);
  }
}

// ---------- w_out [1024][1024] -> transposed bf16 [n][k] (coalesced) ----------
__global__ __launch_bounds__(256) void prep_wo_k(const float* __restrict__ w,
    unsigned short* __restrict__ wt){
  __shared__ float tile[32][33];
  int tx = threadIdx.x & 31, ty = threadIdx.x >> 5;
  int n0 = blockIdx.x * 32, k0 = blockIdx.y * 32;
  #pragma unroll
  for (int i = 0; i < 32; i += 8)
    tile[ty + i][tx] = w[(size_t)(k0 + ty + i) * NE + n0 + tx];
  __syncthreads();
  #pragma unroll
  for (int i = 0; i < 32; i += 8)
    wt[(size_t)(n0 + ty + i) * NE + k0 + tx] = f2bf(tile[tx][ty + i]);
}

// ---------- 128x128 GEMM (B^T layout), single-term ----------
// EPI=0: bf16 inputs, Cf[row*N+col] = acc (fp32)
// EPI=1: fp16 inputs, fused QKV scatter: col = kk*1024+h*64+d ->
//        kk=0: Q fp16; kk=1: K fp16 hi/lo; kk=2: V fp16 transposed
// NOTE r21: XCD block swizzle here caused nondeterministic post-timing
// divergence (first call passed, replays diverged). Reverted — do not retry
// without a race diagnosis.
template<int EPI>
__global__ __launch_bounds__(256) void gemm_k(
    const unsigned short* __restrict__ A,    // [M][K]
    const unsigned short* __restrict__ Bt,   // [N][K]
    float* __restrict__ Cf,
    unsigned short* __restrict__ Qh,
    unsigned short* __restrict__ Kh, unsigned short* __restrict__ Kl,
    unsigned short* __restrict__ Vt,
    int M, int N, int K){
  __shared__ unsigned short lds[2][128 * 32];
  const int tid = threadIdx.x;
  const int w = tid >> 6, l = tid & 63;
  const int wr = w >> 1, wc = w & 1;
  const int m0 = blockIdx.y * 128, n0 = blockIdx.x * 128;

  f32x4 acc[4][4];
  #pragma unroll
  for (int i = 0; i < 4; i++)
    #pragma unroll
    for (int j = 0; j < 4; j++) acc[i][j] = (f32x4){0.f, 0.f, 0.f, 0.f};

  const int lr = l >> 2;
  const int lkb = (l & 3) * 8;

  for (int k0 = 0; k0 < K; k0 += 32){
    #pragma unroll
    for (int cc = 0; cc < 2; cc++){
      int c = w + cc * 4;
      gload_lds16(A  + (size_t)(m0 + c * 16 + lr) * K + k0 + lkb, &lds[0][c * 512]);
      gload_lds16(Bt + (size_t)(n0 + c * 16 + lr) * K + k0 + lkb, &lds[1][c * 512]);
    }
    __syncthreads();
    bf16x8 af[4], bfr[4];
    #pragma unroll
    for (int mi = 0; mi < 4; mi++)
      af[mi] = *(bf16x8*)&lds[0][(wr * 64 + mi * 16 + (l & 15)) * 32 + (l >> 4) * 8];
    #pragma unroll
    for (int ni = 0; ni < 4; ni++)
      bfr[ni] = *(bf16x8*)&lds[1][(wc * 64 + ni * 16 + (l & 15)) * 32 + (l >> 4) * 8];
    #pragma unroll
    for (int mi = 0; mi < 4; mi++)
      #pragma unroll
      for (int ni = 0; ni < 4; ni++)
        acc[mi][ni] = EPI ? mfma16h(af[mi], bfr[ni], acc[mi][ni])
                          : mfma16b(af[mi], bfr[ni], acc[mi][ni]);
    __syncthreads();
  }

  #pragma unroll
  for (int mi = 0; mi < 4; mi++){
    #pragma unroll
    for (int ni = 0; ni < 4; ni++){
      #pragma unroll
      for (int j = 0; j < 4; j++){
        int row = m0 + wr * 64 + mi * 16 + (l >> 4) * 4 + j;
        int col = n0 + wc * 64 + ni * 16 + (l & 15);
        float v = acc[mi][ni][j];
        if (EPI == 0){
          Cf[(size_t)row * N + col] = v;
        } else {
          int kk = col >> 10, h = (col >> 6) & 15, d = col & 63;
          int bb = row >> 11, t = row & (NT - 1);
          if (kk == 2){
            Vt[((size_t)(bb * NH + h) * ND + d) * NT + t] = f2h(v);
          } else {
            size_t off = ((size_t)(bb * NH + h) * NT + t) * ND + d;
            if (kk == 0){
              Qh[off] = f2h(v);                         // single fp16 Q
            } else {
              unsigned short hi = f2h(v);
              Kh[off] = hi; Kl[off] = f2h(v - h2f(hi)); // fp16 hi/lo K
            }
          }
        }
      }
    }
  }
}

// ---------- flash attention, 32x32 fp16 MFMA, LDS-staged K/V, KVBLK=64 ------
// Round-22: round 20 verbatim (295.6us verified incl. post-timing check).
// Each wave owns TWO 32-row q-tiles; grid 512 = 2 blocks/CU. Two-chain QK^T
// (single-chain = NaN codegen trap, r17/r18 — do not retry).
__global__ __launch_bounds__(256, 2) void attn_k(
    const unsigned short* __restrict__ Qh,
    const unsigned short* __restrict__ Kh, const unsigned short* __restrict__ Kl,
    const unsigned short* __restrict__ Vt, unsigned short* __restrict__ O){
  __shared__ unsigned short kh_lds[2][64 * 64];   // 64 kv-rows x 64 d, 8 KB/buf
  __shared__ unsigned short kl_lds[2][64 * 64];
  __shared__ unsigned short vt_lds[2][64 * 64];   // 64 d-rows x 64 t, 8 KB/buf
  const int tid = threadIdx.x;
  const int w = tid >> 6, l = tid & 63;
  const int qi = l & 31, hi = l >> 5;
  const int bid = blockIdx.x;
  const int xcd = bid & 7, slot = bid >> 3;      // slot 0..63
  const int bh_i = xcd + 8 * (slot >> 3);        // 0..63, fixed per XCD group
  const int qt = slot & 7;
  const int b = bh_i >> 4, h = bh_i & 15;
  const int i0A = qt * 256 + w * 32;
  const int i0B = i0A + 128;
  const size_t bh = (size_t)bh_i;

  const unsigned short* KhG = Kh + bh * NT * ND;
  const unsigned short* KlG = Kl + bh * NT * ND;
  const unsigned short* VtG = Vt + bh * ND * NT;

  bf16x8 qhA[4], qhB[4];                          // fp16 payload
  {
    const unsigned short* qa = Qh + (bh * NT + i0A + qi) * ND + hi * 8;
    const unsigned short* qb = Qh + (bh * NT + i0B + qi) * ND + hi * 8;
    #pragma unroll
    for (int c = 0; c < 4; c++){
      qhA[c] = *(const bf16x8*)(qa + c * 16);
      qhB[c] = *(const bf16x8*)(qb + c * 16);
    }
  }

  f32x16 oA0, oA1, oB0, oB1;
  #pragma unroll
  for (int r = 0; r < 16; r++){ oA0[r] = 0.f; oA1[r] = 0.f; oB0[r] = 0.f; oB1[r] = 0.f; }
  float mrunA = -3.0e38f, lrunA = 0.f;
  float mrunB = -3.0e38f, lrunB = 0.f;

  // staging lanes: 8 rows per gload (8 lanes/row); wave w owns rows 16w..16w+15
  const int rk = l >> 3;                       // local row 0..7 within group
  const int ck = (l & 7) ^ rk;                 // swizzled source chunk

  auto STAGE = [&](int buf, int j0){
    gload_lds16(KhG + (size_t)(j0 + 16 * w + rk) * ND + ck * 8,     &kh_lds[buf][(16 * w) * 64]);
    gload_lds16(KhG + (size_t)(j0 + 16 * w + 8 + rk) * ND + ck * 8, &kh_lds[buf][(16 * w + 8) * 64]);
    gload_lds16(KlG + (size_t)(j0 + 16 * w + rk) * ND + ck * 8,     &kl_lds[buf][(16 * w) * 64]);
    gload_lds16(KlG + (size_t)(j0 + 16 * w + 8 + rk) * ND + ck * 8, &kl_lds[buf][(16 * w + 8) * 64]);
    gload_lds16(VtG + (size_t)(16 * w + rk) * NT + j0 + ck * 8,     &vt_lds[buf][(16 * w) * 64]);
    gload_lds16(VtG + (size_t)(16 * w + 8 + rk) * NT + j0 + ck * 8, &vt_lds[buf][(16 * w + 8) * 64]);
  };

  auto STEP = [&](int buf, int half, const bf16x8 (&qh)[4],
                  f32x16& o0, f32x16& o1, float& mrun, float& lrun){
    const char* KH = (const char*)&kh_lds[buf][0];
    const char* KL = (const char*)&kl_lds[buf][0];
    const char* VT = (const char*)&vt_lds[buf][0];
    // K fragments: row half*32+qi, chunk 2c+hi, swizzled slot (row&7 = qi&7)
    bf16x8 kh[4], kl[4];
    #pragma unroll
    for (int c = 0; c < 4; c++){
      int off = (half * 32 + qi) * 128 + (((2 * c + hi) ^ (qi & 7)) * 16);
      kh[c] = *(const bf16x8*)(KH + off);
      kl[c] = *(const bf16x8*)(KL + off);
    }

    // 2-chain fp16 QK^T: S = qh*kh + qh*kl  (K = kh+kl near-exact)
    f32x16 t1, t2;
    #pragma unroll
    for (int r = 0; r < 16; r++){ t1[r] = 0.f; t2[r] = 0.f; }
    __builtin_amdgcn_s_setprio(1);
    #pragma unroll
    for (int c = 0; c < 4; c++){
      t1 = mfma32h(kh[c], qh[c], t1);
      t2 = mfma32h(kl[c], qh[c], t2);
    }
    __builtin_amdgcn_s_setprio(0);
    f32x16 s = t1 + t2;

    // V fragments (issue early): d-row dt*32+qi, t-slot half*4+2k0+hi
    bf16x8 vb[2][2];
    #pragma unroll
    for (int dt = 0; dt < 2; dt++)
      #pragma unroll
      for (int k0 = 0; k0 < 2; k0++){
        int off = (dt * 32 + qi) * 128 + (((half * 4 + 2 * k0 + hi) ^ (qi & 7)) * 16);
        vb[dt][k0] = *(const bf16x8*)(VT + off);
      }

    // online softmax; stats indexed by q = lane&31; max3 tree
    float m1 = max3f(s[0], s[1], s[2]);
    float m2 = max3f(s[3], s[4], s[5]);
    float m3 = max3f(s[6], s[7], s[8]);
    float m4 = max3f(s[9], s[10], s[11]);
    float m5 = max3f(s[12], s[13], s[14]);
    float pm = fmaxf(max3f(m1, m2, m3), max3f(m4, m5, s[15]));
    pm = fmaxf(pm, __shfl_xor(pm, 32));
    float Lm = pm * 8.0f;
    if (!__all(Lm <= mrun + 8.0f)){      // defer-max (T13), THR=8
      float nm = fmaxf(mrun, Lm);
      float sc = __expf(mrun - nm);
      mrun = nm;
      lrun *= sc;
      #pragma unroll
      for (int r = 0; r < 16; r++){      // O row = crow(r,hi): gather row's sc
        int mrow = (r & 3) + 8 * (r >> 2) + 4 * hi;
        float scr = __shfl(sc, mrow);
        o0[r] *= scr;
        o1[r] *= scr;
      }
    }
    float p[16];
    #pragma unroll
    for (int r = 0; r < 16; r++) p[r] = __expf(fmaf(s[r], 8.0f, -mrun));
    float u8[8], u4[4];
    #pragma unroll
    for (int i = 0; i < 8; i++) u8[i] = p[2 * i] + p[2 * i + 1];
    #pragma unroll
    for (int i = 0; i < 4; i++) u4[i] = u8[2 * i] + u8[2 * i + 1];
    float rs = (u4[0] + u4[1]) + (u4[2] + u4[3]);
    rs += __shfl_xor(rs, 32);
    lrun += rs;

    // P -> fp16 via packed cvt, then lane<->lane+32 exchange (no LDS)
    unsigned int pk[8];
    #pragma unroll
    for (int i = 0; i < 8; i++)
      asm("v_cvt_pkrtz_f16_f32 %0, %1, %2" : "=v"(pk[i]) : "v"(p[2 * i]), "v"(p[2 * i + 1]));
    unsigned int sw[8];
    #pragma unroll
    for (int i = 0; i < 8; i++) sw[i] = __shfl_xor(pk[i], 32);

    union { unsigned int u[4]; bf16x8 v; } pa0, pa1;
    pa0.u[0] = hi ? sw[2] : pk[0];
    pa0.u[1] = hi ? sw[3] : pk[1];
    pa0.u[2] = hi ? pk[2] : sw[0];
    pa0.u[3] = hi ? pk[3] : sw[1];
    pa1.u[0] = hi ? sw[6] : pk[4];
    pa1.u[1] = hi ? sw[7] : pk[5];
    pa1.u[2] = hi ? pk[6] : sw[4];
    pa1.u[3] = hi ? pk[7] : sw[5];

    __builtin_amdgcn_s_setprio(1);
    o0 = mfma32h(pa0.v, vb[0][0], o0);
    o0 = mfma32h(pa1.v, vb[0][1], o0);
    o1 = mfma32h(pa0.v, vb[1][0], o1);
    o1 = mfma32h(pa1.v, vb[1][1], o1);
    __builtin_amdgcn_s_setprio(0);
  };

  STAGE(0, 0);
  asm volatile("s_waitcnt vmcnt(0)" ::: "memory");
  __syncthreads();
  int buf = 0;
  for (int j0 = 0; j0 < NT; j0 += 64){
    if (j0 + 64 < NT) STAGE(buf ^ 1, j0 + 64);   // prefetch next 64-kv tile
    STEP(buf, 0, qhA, oA0, oA1, mrunA, lrunA);
    STEP(buf, 1, qhA, oA0, oA1, mrunA, lrunA);
    STEP(buf, 0, qhB, oB0, oB1, mrunB, lrunB);
    STEP(buf, 1, qhB, oB0, oB1, mrunB, lrunB);
    __syncthreads();                              // drains vmcnt+lgkm, then barrier
    buf ^= 1;
  }

  // normalize (lrun for row mrow lives in lane mrow) and store (bf16 Obuf)
  float rlA = 1.0f / lrunA;
  float rlB = 1.0f / lrunB;
  #pragma unroll
  for (int r = 0; r < 16; r++){
    int mrow = (r & 3) + 8 * (r >> 2) + 4 * hi;
    float fA = __shfl(rlA, mrow);
    float fB = __shfl(rlB, mrow);
    size_t baseA = ((size_t)b * NT + i0A + mrow) * NE + h * ND + qi;
    size_t baseB = ((size_t)b * NT + i0B + mrow) * NE + h * ND + qi;
    O[baseA]      = f2bf(oA0[r] * fA);
    O[baseA + 32] = f2bf(oA1[r] * fA);
    O[baseB]      = f2bf(oB0[r] * fB);
    O[baseB + 32] = f2bf(oB1[r] * fB);
  }
}

extern "C" void kernel_launch(void* const* d_in, const int* in_sizes, int n_in,
                              void* d_out, int out_size, void* d_ws, size_t ws_size,
                              hipStream_t stream){
  const float* x     = (const float*)d_in[0];
  const float* w_qkv = (const float*)d_in[1];
  const float* w_out = (const float*)d_in[2];
  float* out = (float*)d_out;

  char* ws = (char*)d_ws;
  const size_t SZ_X  = (size_t)NM * NE * 2;          // 16.78 MB
  const size_t SZ_WQ = (size_t)3072 * NE * 2;        // 6.29 MB
  const size_t SZ_WO = (size_t)NE * NE * 2;          // 2.10 MB
  const size_t SZ_T  = (size_t)NB * NH * NT * ND * 2;// 16.78 MB

  unsigned short* xh  = (unsigned short*)(ws);
  unsigned short* wq  = (unsigned short*)(ws + SZ_X);
  unsigned short* wto = (unsigned short*)(ws + SZ_X + SZ_WQ);
  unsigned short* Qh  = (unsigned short*)(ws + SZ_X + SZ_WQ + SZ_WO);
  unsigned short* Kh  = Qh + (SZ_T / 2);
  unsigned short* Kl  = Qh + 2 * (SZ_T / 2);
  unsigned short* Vt  = Qh + 3 * (SZ_T / 2);   // own slot (x live during fused GEMM)
  unsigned short* Obuf = xh;                   // x dead after fused GEMM

  const size_t NEED = SZ_X + SZ_WQ + SZ_WO + 4 * SZ_T;  // ~92 MB
  if (ws_size < NEED) return;

  prep_x_k<<<2048, 256, 0, stream>>>(x, xh, NM * NE / 4);
  prep_wq_k<<<dim3(3072 / 32, 1024 / 32), 256, 0, stream>>>(w_qkv, wq);
  prep_wo_k<<<dim3(1024 / 32, 1024 / 32), 256, 0, stream>>>(w_out, wto);
  // fused QKV projection: single-term fp16, N=3072
  gemm_k<1><<<dim3(3072 / 128, NM / 128), 256, 0, stream>>>(
      xh, wq, nullptr, Qh, Kh, Kl, Vt, NM, 3072, NE);
  attn_k<<<dim3(512), 256, 0, stream>>>(Qh, Kh, Kl, Vt, Obuf);
  gemm_k<0><<<dim3(NE / 128, NM / 128), 256, 0, stream>>>(
      Obuf, wto, out, nullptr, nullptr, nullptr, nullptr, NM, NE, NE);
}